// Round 3
// baseline (352.951 us; speedup 1.0000x reference)
//
#include <hip/hip_runtime.h>

#define LSEQ 4096
#define HDIM 768
#define NHEAD 12

using v4f    = __attribute__((ext_vector_type(4))) float;
using short8 = __attribute__((ext_vector_type(8))) short;
using u32x4  = __attribute__((ext_vector_type(4))) unsigned int;

__device__ __forceinline__ unsigned short f2bf(float f) {
  union { float f; unsigned u; } v; v.f = f;
  unsigned r = v.u + 0x7fffu + ((v.u >> 16) & 1u);
  return (unsigned short)(r >> 16);
}

// Load 8 consecutive fp32 elements at element-offset `off`, convert to bf16x8.
__device__ __forceinline__ short8 ld8(const float* p, size_t off) {
  const float* f = p + off;
  float t[8];
  *(u32x4*)&t[0] = *(const u32x4*)(f);
  *(u32x4*)&t[4] = *(const u32x4*)(f + 4);
  short8 r;
#pragma unroll
  for (int i = 0; i < 8; ++i) r[i] = (short)f2bf(t[i]);
  return r;
}

// ---------------------------------------------------------------------------
// QKV projection: Y[m][n] = sum_k X[m][k] * W[n][k] + b[n]   (fp32 in, bf16 out)
// Tile 128x128, BK=32, bf16 MFMA 16x16x32. grid = (6, 32, 3); z picks q/k/v.
// dst layout: [NH][L][64] bf16 head-major.
// ---------------------------------------------------------------------------
__global__ __launch_bounds__(256, 2) void proj_gemm(
    const float* __restrict__ Xq, const float* __restrict__ Xk,
    const float* __restrict__ Xv,
    const float* __restrict__ Wq, const float* __restrict__ Wk,
    const float* __restrict__ Wv,
    const float* __restrict__ bq, const float* __restrict__ bk,
    const float* __restrict__ bv,
    unsigned short* __restrict__ dst_base)
{
  __shared__ __align__(16) unsigned short a_lds[128 * 32];
  __shared__ __align__(16) unsigned short b_lds[128 * 32];

  const int z = blockIdx.z;
  const float* X = (z == 0) ? Xq : ((z == 1) ? Xk : Xv);
  const float* W = (z == 0) ? Wq : ((z == 1) ? Wk : Wv);
  const float* bias = (z == 0) ? bq : ((z == 1) ? bk : bv);
  unsigned short* dst = dst_base + (size_t)z * NHEAD * LSEQ * 64;

  const int tid = threadIdx.x;
  const int wave = tid >> 6, lane = tid & 63;
  const int quad = lane >> 4, l16 = lane & 15;
  const int wm = (wave >> 1) * 64, wn = (wave & 1) * 64;
  const int bm = blockIdx.y * 128, bn = blockIdx.x * 128;

  v4f acc[4][4];
  for (int i = 0; i < 4; ++i)
    for (int j = 0; j < 4; ++j)
      acc[i][j] = (v4f){0.f, 0.f, 0.f, 0.f};

  const int row_s = tid >> 2;         // 0..63
  const int c8_s = (tid & 3) * 8;     // 0,8,16,24

  for (int k0 = 0; k0 < HDIM; k0 += 32) {
    __syncthreads();
    for (int s = 0; s < 2; ++s) {
      int row = row_s + s * 64;
      *(short8*)&a_lds[row * 32 + c8_s] = ld8(X, (size_t)(bm + row) * HDIM + k0 + c8_s);
      *(short8*)&b_lds[row * 32 + c8_s] = ld8(W, (size_t)(bn + row) * HDIM + k0 + c8_s);
    }
    __syncthreads();

    short8 af[4], bfr[4];
    for (int i = 0; i < 4; ++i)
      af[i] = *(const short8*)&a_lds[(wm + i * 16 + l16) * 32 + quad * 8];
    for (int j = 0; j < 4; ++j)
      bfr[j] = *(const short8*)&b_lds[(wn + j * 16 + l16) * 32 + quad * 8];
    for (int i = 0; i < 4; ++i)
      for (int j = 0; j < 4; ++j)
        acc[i][j] = __builtin_amdgcn_mfma_f32_16x16x32_bf16(af[i], bfr[j], acc[i][j], 0, 0, 0);
  }

  // epilogue: C row = (quad*4 + r), col = l16  [verified m89/m91 layout]
  for (int j = 0; j < 4; ++j) {
    int n = bn + wn + j * 16 + l16;
    float bias_v = bias[n];
    int hh = n >> 6, d = n & 63;
    for (int i = 0; i < 4; ++i)
      for (int r = 0; r < 4; ++r) {
        int m = bm + wm + i * 16 + quad * 4 + r;
        dst[((size_t)hh * LSEQ + m) * 64 + d] = f2bf(acc[i][j][r] + bias_v);
      }
  }
}

// ---------------------------------------------------------------------------
// Flash attention: grid = (64, 12), block = 256 (4 waves).
// Wave w owns q-rows [qt*64 + w*16, +16); loops over 64 key-tiles of 64.
// Q/K/V from ws (bf16 head-major); mask/out fp32.
// ---------------------------------------------------------------------------
__global__ __launch_bounds__(256, 2) void attn(
    const unsigned short* __restrict__ Q, const unsigned short* __restrict__ K,
    const unsigned short* __restrict__ V, const float* __restrict__ mask,
    float* __restrict__ out)
{
  __shared__ __align__(16) unsigned short k_lds[2][64 * 32];  // [khalf][key][32]
  __shared__ __align__(16) unsigned short vt_lds[64 * 64];    // [d][key] xor-swizzled
  __shared__ __align__(16) unsigned short p_lds[4][16 * 72];  // per-wave P round-trip
  __shared__ float mask_lds[LSEQ];

  const int h = blockIdx.y;
  const int qt = blockIdx.x;
  const int tid = threadIdx.x;
  const int wave = tid >> 6, lane = tid & 63;
  const int quad = lane >> 4, l16 = lane & 15;

  // mask -> f32 LDS, once
  for (int i = tid; i < LSEQ; i += 256) mask_lds[i] = mask[i];

  const unsigned short* Qh = Q + (size_t)h * LSEQ * 64;
  const unsigned short* Kh = K + (size_t)h * LSEQ * 64;
  const unsigned short* Vh = V + (size_t)h * LSEQ * 64;

  const int qrow = qt * 64 + wave * 16;
  short8 qf[2];
  for (int c = 0; c < 2; ++c)
    qf[c] = *(const short8*)(Qh + (size_t)(qrow + l16) * 64 + c * 32 + quad * 8);

  v4f acc_o[4];
  for (int j = 0; j < 4; ++j) acc_o[j] = (v4f){0.f, 0.f, 0.f, 0.f};
  float m_i[4] = {-INFINITY, -INFINITY, -INFINITY, -INFINITY};
  float l_i[4] = {0.f, 0.f, 0.f, 0.f};

  for (int kt = 0; kt < 64; ++kt) {
    const int key0 = kt * 64;
    __syncthreads();  // prior tile's LDS readers done

    // stage K tile [64 keys][64] as two [64][32] halves
    for (int s = 0; s < 2; ++s) {
      int ch = tid + 256 * s;
      int row = ch >> 3, c8 = ch & 7;
      *(u32x4*)&k_lds[c8 >> 2][row * 32 + (c8 & 3) * 8] =
          *(const u32x4*)(Kh + (size_t)(key0 + row) * 64 + c8 * 8);
    }
    // stage V transposed: vt[d][key], key-block xor-swizzled by (d&7)
    for (int s = 0; s < 2; ++s) {
      int ch = tid + 256 * s;
      int key = ch & 63, c8v = ch >> 6;  // c8v: s=0 -> 0..3, s=1 -> 4..7
      u32x4 vv = *(const u32x4*)(Vh + (size_t)(key0 + key) * 64 + c8v * 8);
      int khi = key >> 3, klo = key & 7;
      for (int j = 0; j < 8; ++j) {
        unsigned w = vv[j >> 1];
        unsigned short el = (j & 1) ? (unsigned short)(w >> 16) : (unsigned short)(w & 0xffffu);
        int d = c8v * 8 + j;
        vt_lds[d * 64 + ((khi ^ j) << 3) + klo] = el;
      }
    }
    __syncthreads();

    // S = Q K^T  (rows = q, cols = key)
    v4f sacc[4];
    for (int j = 0; j < 4; ++j) sacc[j] = (v4f){0.f, 0.f, 0.f, 0.f};
    for (int c = 0; c < 2; ++c)
      for (int j = 0; j < 4; ++j) {
        short8 kf = *(const short8*)&k_lds[c][(j * 16 + l16) * 32 + quad * 8];
        sacc[j] = __builtin_amdgcn_mfma_f32_16x16x32_bf16(qf[c], kf, sacc[j], 0, 0, 0);
      }

    // scale + mask
    float sv[4][4];
    for (int j = 0; j < 4; ++j) {
      float mk = mask_lds[key0 + j * 16 + l16];
      for (int r = 0; r < 4; ++r) sv[j][r] = sacc[j][r] * 0.125f + mk;
    }

    // online softmax: row r lives on lanes sharing quad; reduce over l16
    float alpha[4];
    for (int r = 0; r < 4; ++r) {
      float t = fmaxf(fmaxf(sv[0][r], sv[1][r]), fmaxf(sv[2][r], sv[3][r]));
      for (int off = 8; off; off >>= 1) t = fmaxf(t, __shfl_xor(t, off, 64));
      float mn = fmaxf(m_i[r], t);
      alpha[r] = __expf(m_i[r] - mn);
      m_i[r] = mn;
    }
    float pv[4][4];
    for (int r = 0; r < 4; ++r) {
      float s = 0.f;
      for (int j = 0; j < 4; ++j) {
        float p = __expf(sv[j][r] - m_i[r]);
        pv[j][r] = p;
        s += p;
      }
      for (int off = 8; off; off >>= 1) s += __shfl_xor(s, off, 64);
      l_i[r] = l_i[r] * alpha[r] + s;
    }
    for (int j = 0; j < 4; ++j)
      for (int r = 0; r < 4; ++r) acc_o[j][r] *= alpha[r];

    // P: C-layout -> LDS -> A-layout (per-wave region; stride 72 covers 64 cols)
    for (int j = 0; j < 4; ++j)
      for (int r = 0; r < 4; ++r)
        p_lds[wave][(quad * 4 + r) * 72 + j * 16 + l16] = f2bf(pv[j][r]);
    short8 pf[2];
    for (int c = 0; c < 2; ++c)
      pf[c] = *(const short8*)&p_lds[wave][l16 * 72 + c * 32 + quad * 8];

    // O += P V
    for (int c = 0; c < 2; ++c)
      for (int j = 0; j < 4; ++j) {
        short8 vf = *(const short8*)&vt_lds[(j * 16 + l16) * 64 +
                                            (((c * 4 + quad) ^ (l16 & 7)) << 3)];
        acc_o[j] = __builtin_amdgcn_mfma_f32_16x16x32_bf16(pf[c], vf, acc_o[j], 0, 0, 0);
      }
  }

  // epilogue: out[l][h*64 + d] fp32
  for (int j = 0; j < 4; ++j) {
    int col = h * 64 + j * 16 + l16;
    for (int r = 0; r < 4; ++r) {
      int row = qt * 64 + wave * 16 + quad * 4 + r;
      out[(size_t)row * HDIM + col] = acc_o[j][r] / l_i[r];
    }
  }
}

extern "C" void kernel_launch(void* const* d_in, const int* in_sizes, int n_in,
                              void* d_out, int out_size, void* d_ws, size_t ws_size,
                              hipStream_t stream) {
  const float* query = (const float*)d_in[0];
  const float* key   = (const float*)d_in[1];
  const float* value = (const float*)d_in[2];
  const float* mask  = (const float*)d_in[3];
  const float* Wq = (const float*)d_in[4];
  const float* bq = (const float*)d_in[5];
  const float* Wk = (const float*)d_in[6];
  const float* bk = (const float*)d_in[7];
  const float* Wv = (const float*)d_in[8];
  const float* bv = (const float*)d_in[9];
  float* out = (float*)d_out;

  // ws usage: exactly 3 * NHEAD*LSEQ*64 bf16 = 18,874,368 bytes. Nothing more —
  // round-2 post-timing divergence traced to a 4-byte flag past this boundary
  // clobbering an adjacent pristine-input buffer.
  unsigned short* Qb = (unsigned short*)d_ws;                  // [NH][L][64] bf16
  unsigned short* Kb = Qb + (size_t)NHEAD * LSEQ * 64;
  unsigned short* Vb = Kb + (size_t)NHEAD * LSEQ * 64;

  proj_gemm<<<dim3(HDIM / 128, LSEQ / 128, 3), 256, 0, stream>>>(
      query, key, value, Wq, Wk, Wv, bq, bk, bv, Qb);
  attn<<<dim3(LSEQ / 64, NHEAD), 256, 0, stream>>>(Qb, Kb, Vb, mask, out);
}

// Round 4
// 277.202 us; speedup vs baseline: 1.2733x; 1.2733x over previous
//
#include <hip/hip_runtime.h>
#include <math.h>

#define LSEQ 4096
#define HDIM 768
#define NHEAD 12

using v4f    = __attribute__((ext_vector_type(4))) float;
using short8 = __attribute__((ext_vector_type(8))) short;
using u32x4  = __attribute__((ext_vector_type(4))) unsigned int;
using u32x2  = __attribute__((ext_vector_type(2))) unsigned int;

__device__ __forceinline__ unsigned short f2bf(float f) {
  union { float f; unsigned u; } v; v.f = f;
  unsigned r = v.u + 0x7fffu + ((v.u >> 16) & 1u);
  return (unsigned short)(r >> 16);
}

// Load 8 consecutive fp32 elements at element-offset `off`, convert to bf16x8.
__device__ __forceinline__ short8 ld8(const float* p, size_t off) {
  const float* f = p + off;
  float t[8];
  *(u32x4*)&t[0] = *(const u32x4*)(f);
  *(u32x4*)&t[4] = *(const u32x4*)(f + 4);
  short8 r;
#pragma unroll
  for (int i = 0; i < 8; ++i) r[i] = (short)f2bf(t[i]);
  return r;
}

// ---------------------------------------------------------------------------
// QKV projection: Y[m][n] = sum_k X[m][k] * W[n][k] + b[n]   (fp32 in, bf16 out)
// Tile 128x128, BK=32, bf16 MFMA 16x16x32. grid = (6, 32, 3); z picks q/k/v.
// Q,K dst: [NH][L][64] head-major.  V dst: [NH][64][L] (pre-transposed for attn).
// ---------------------------------------------------------------------------
__global__ __launch_bounds__(256, 2) void proj_gemm(
    const float* __restrict__ Xq, const float* __restrict__ Xk,
    const float* __restrict__ Xv,
    const float* __restrict__ Wq, const float* __restrict__ Wk,
    const float* __restrict__ Wv,
    const float* __restrict__ bq, const float* __restrict__ bk,
    const float* __restrict__ bv,
    unsigned short* __restrict__ dst_base)
{
  __shared__ __align__(16) unsigned short a_lds[128 * 32];
  __shared__ __align__(16) unsigned short b_lds[128 * 32];

  const int z = blockIdx.z;
  const float* X = (z == 0) ? Xq : ((z == 1) ? Xk : Xv);
  const float* W = (z == 0) ? Wq : ((z == 1) ? Wk : Wv);
  const float* bias = (z == 0) ? bq : ((z == 1) ? bk : bv);
  unsigned short* dst = dst_base + (size_t)z * NHEAD * LSEQ * 64;

  const int tid = threadIdx.x;
  const int wave = tid >> 6, lane = tid & 63;
  const int quad = lane >> 4, l16 = lane & 15;
  const int wm = (wave >> 1) * 64, wn = (wave & 1) * 64;
  const int bm = blockIdx.y * 128, bn = blockIdx.x * 128;

  v4f acc[4][4];
  for (int i = 0; i < 4; ++i)
    for (int j = 0; j < 4; ++j)
      acc[i][j] = (v4f){0.f, 0.f, 0.f, 0.f};

  const int row_s = tid >> 2;         // 0..63
  const int c8_s = (tid & 3) * 8;     // 0,8,16,24

  for (int k0 = 0; k0 < HDIM; k0 += 32) {
    __syncthreads();
    for (int s = 0; s < 2; ++s) {
      int row = row_s + s * 64;
      *(short8*)&a_lds[row * 32 + c8_s] = ld8(X, (size_t)(bm + row) * HDIM + k0 + c8_s);
      *(short8*)&b_lds[row * 32 + c8_s] = ld8(W, (size_t)(bn + row) * HDIM + k0 + c8_s);
    }
    __syncthreads();

    short8 af[4], bfr[4];
    for (int i = 0; i < 4; ++i)
      af[i] = *(const short8*)&a_lds[(wm + i * 16 + l16) * 32 + quad * 8];
    for (int j = 0; j < 4; ++j)
      bfr[j] = *(const short8*)&b_lds[(wn + j * 16 + l16) * 32 + quad * 8];
    for (int i = 0; i < 4; ++i)
      for (int j = 0; j < 4; ++j)
        acc[i][j] = __builtin_amdgcn_mfma_f32_16x16x32_bf16(af[i], bfr[j], acc[i][j], 0, 0, 0);
  }

  // epilogue: C row = (quad*4 + r), col = l16  [verified m89/m91 layout]
  for (int j = 0; j < 4; ++j) {
    int n = bn + wn + j * 16 + l16;
    float bias_v = bias[n];
    int hh = n >> 6, d = n & 63;
    if (z == 2) {
      // V transposed: [NH][64][LSEQ]; r=0..3 are consecutive seq -> 8B packed store
      for (int i = 0; i < 4; ++i) {
        int m = bm + wm + i * 16 + quad * 4;
        unsigned short tmp[4];
        for (int r = 0; r < 4; ++r) tmp[r] = f2bf(acc[i][j][r] + bias_v);
        *(u32x2*)&dst[((size_t)hh * 64 + d) * LSEQ + m] = *(const u32x2*)tmp;
      }
    } else {
      for (int i = 0; i < 4; ++i)
        for (int r = 0; r < 4; ++r) {
          int m = bm + wm + i * 16 + quad * 4 + r;
          dst[((size_t)hh * LSEQ + m) * 64 + d] = f2bf(acc[i][j][r] + bias_v);
        }
    }
  }
}

// ---------------------------------------------------------------------------
// Flash attention (no-max softmax: scores bounded ~|1.7|, fp32 exp safe, and
// softmax is shift-invariant -> identical result, no per-tile reductions).
// grid = (64, 12), block = 256 (4 waves). Wave w owns q-rows [qt*64+w*16, +16).
// Q,K from ws [NH][L][64]; V from ws pre-transposed [NH][64][L]; mask/out fp32.
// ---------------------------------------------------------------------------
__global__ __launch_bounds__(256, 2) void attn(
    const unsigned short* __restrict__ Q, const unsigned short* __restrict__ K,
    const unsigned short* __restrict__ Vt, const float* __restrict__ mask,
    float* __restrict__ out)
{
  __shared__ __align__(16) unsigned short k_lds[2][64 * 32];  // [dhalf][key][32]
  __shared__ __align__(16) unsigned short vt_lds[64 * 64];    // [d][key] xor-swizzled
  __shared__ __align__(16) unsigned short p_lds[4][16 * 72];  // per-wave P round-trip
  __shared__ float mask_lds[LSEQ];                            // mask * log2e

  const int h = blockIdx.y;
  const int qt = blockIdx.x;
  const int tid = threadIdx.x;
  const int wave = tid >> 6, lane = tid & 63;
  const int quad = lane >> 4, l16 = lane & 15;

  for (int i = tid; i < LSEQ; i += 256) mask_lds[i] = mask[i] * 1.44269504f;

  const unsigned short* Qh  = Q  + (size_t)h * LSEQ * 64;
  const unsigned short* Kh  = K  + (size_t)h * LSEQ * 64;
  const unsigned short* Vth = Vt + (size_t)h * 64 * LSEQ;

  const int qrow = qt * 64 + wave * 16;
  short8 qf[2];
  for (int c = 0; c < 2; ++c)
    qf[c] = *(const short8*)(Qh + (size_t)(qrow + l16) * 64 + c * 32 + quad * 8);

  v4f acc_o[4];
  for (int j = 0; j < 4; ++j) acc_o[j] = (v4f){0.f, 0.f, 0.f, 0.f};
  float lsum[4] = {0.f, 0.f, 0.f, 0.f};

  for (int kt = 0; kt < 64; ++kt) {
    const int key0 = kt * 64;
    __syncthreads();  // prior tile's LDS readers done

    // stage K tile [64 keys][64] as two [64][32] halves (vectorized)
    for (int s = 0; s < 2; ++s) {
      int ch = tid + 256 * s;
      int row = ch >> 3, c8 = ch & 7;
      *(u32x4*)&k_lds[c8 >> 2][row * 32 + (c8 & 3) * 8] =
          *(const u32x4*)(Kh + (size_t)(key0 + row) * 64 + c8 * 8);
    }
    // stage V^T tile: vt[d][key], 8-key chunks xor-swizzled by (d&7) (vectorized)
    for (int s = 0; s < 2; ++s) {
      int ch = tid + 256 * s;
      int d = ch >> 3, kb = ch & 7;
      *(u32x4*)&vt_lds[d * 64 + ((kb ^ (d & 7)) << 3)] =
          *(const u32x4*)(Vth + (size_t)d * LSEQ + key0 + kb * 8);
    }
    __syncthreads();

    // S = Q K^T  (rows = q, cols = key)
    v4f sacc[4];
    for (int j = 0; j < 4; ++j) sacc[j] = (v4f){0.f, 0.f, 0.f, 0.f};
    for (int c = 0; c < 2; ++c)
      for (int j = 0; j < 4; ++j) {
        short8 kf = *(const short8*)&k_lds[c][(j * 16 + l16) * 32 + quad * 8];
        sacc[j] = __builtin_amdgcn_mfma_f32_16x16x32_bf16(qf[c], kf, sacc[j], 0, 0, 0);
      }

    // p = exp2(s*scale*log2e + mask*log2e); accumulate per-lane row sums
    for (int j = 0; j < 4; ++j) {
      float mk = mask_lds[key0 + j * 16 + l16];
      for (int r = 0; r < 4; ++r) {
        float p = exp2f(fmaf(sacc[j][r], 0.18033688f, mk));
        lsum[r] += p;
        p_lds[wave][(quad * 4 + r) * 72 + j * 16 + l16] = f2bf(p);
      }
    }
    short8 pf[2];
    for (int c = 0; c < 2; ++c)
      pf[c] = *(const short8*)&p_lds[wave][l16 * 72 + c * 32 + quad * 8];

    // O += P V
    for (int c = 0; c < 2; ++c)
      for (int j = 0; j < 4; ++j) {
        short8 vf = *(const short8*)&vt_lds[(j * 16 + l16) * 64 +
                                            (((c * 4 + quad) ^ (l16 & 7)) << 3)];
        acc_o[j] = __builtin_amdgcn_mfma_f32_16x16x32_bf16(pf[c], vf, acc_o[j], 0, 0, 0);
      }
  }

  // one final reduction of row sums over the 16 l16 lanes (row = quad*4+r)
  for (int r = 0; r < 4; ++r) {
    float s = lsum[r];
    for (int off = 8; off; off >>= 1) s += __shfl_xor(s, off, 64);
    lsum[r] = s;
  }

  // epilogue: out[l][h*64 + d] fp32
  for (int j = 0; j < 4; ++j) {
    int col = h * 64 + j * 16 + l16;
    for (int r = 0; r < 4; ++r) {
      int row = qt * 64 + wave * 16 + quad * 4 + r;
      out[(size_t)row * HDIM + col] = acc_o[j][r] / lsum[r];
    }
  }
}

extern "C" void kernel_launch(void* const* d_in, const int* in_sizes, int n_in,
                              void* d_out, int out_size, void* d_ws, size_t ws_size,
                              hipStream_t stream) {
  const float* query = (const float*)d_in[0];
  const float* key   = (const float*)d_in[1];
  const float* value = (const float*)d_in[2];
  const float* mask  = (const float*)d_in[3];
  const float* Wq = (const float*)d_in[4];
  const float* bq = (const float*)d_in[5];
  const float* Wk = (const float*)d_in[6];
  const float* bk = (const float*)d_in[7];
  const float* Wv = (const float*)d_in[8];
  const float* bv = (const float*)d_in[9];
  float* out = (float*)d_out;

  // ws usage: exactly 3 * NHEAD*LSEQ*64 bf16 = 18,874,368 bytes (known-safe bound).
  unsigned short* Qb = (unsigned short*)d_ws;                  // [NH][L][64] bf16
  unsigned short* Kb = Qb + (size_t)NHEAD * LSEQ * 64;         // [NH][L][64] bf16
  unsigned short* Vb = Kb + (size_t)NHEAD * LSEQ * 64;         // [NH][64][L] bf16 (transposed)

  proj_gemm<<<dim3(HDIM / 128, LSEQ / 128, 3), 256, 0, stream>>>(
      query, key, value, Wq, Wk, Wv, bq, bk, bv, Qb);
  attn<<<dim3(LSEQ / 64, NHEAD), 256, 0, stream>>>(Qb, Kb, Vb, mask, out);
}

// Round 5
// 255.611 us; speedup vs baseline: 1.3808x; 1.0845x over previous
//
#include <hip/hip_runtime.h>
#include <math.h>

#define LSEQ 4096
#define HDIM 768
#define NHEAD 12

using v4f    = __attribute__((ext_vector_type(4))) float;
using short8 = __attribute__((ext_vector_type(8))) short;
using u32x4  = __attribute__((ext_vector_type(4))) unsigned int;

#if __has_builtin(__builtin_amdgcn_exp2f)
#define EXP2F(x) __builtin_amdgcn_exp2f(x)
#else
#define EXP2F(x) exp2f(x)
#endif

__device__ __forceinline__ unsigned short f2bf(float f) {
  union { float f; unsigned u; } v; v.f = f;
  unsigned r = v.u + 0x7fffu + ((v.u >> 16) & 1u);
  return (unsigned short)(r >> 16);
}

// Load 8 consecutive fp32 elements at element-offset `off`, convert to bf16x8.
__device__ __forceinline__ short8 ld8(const float* p, size_t off) {
  const float* f = p + off;
  float t[8];
  *(u32x4*)&t[0] = *(const u32x4*)(f);
  *(u32x4*)&t[4] = *(const u32x4*)(f + 4);
  short8 r;
#pragma unroll
  for (int i = 0; i < 8; ++i) r[i] = (short)f2bf(t[i]);
  return r;
}

// ---------------------------------------------------------------------------
// QKV projection: Y = X W^T + b (fp32 in, bf16 out). Tile 128x128, BK=32.
// grid = (6, 32, 3); z picks q/k/v. Q,K dst: [NH][L][64]. V dst: [NH][64][L]
// (computed transposed by swapping MFMA operands -> C^T in registers).
// Epilogue goes through an LDS C-tile so ALL global stores are coalesced b128.
// ---------------------------------------------------------------------------
__global__ __launch_bounds__(256, 2) void proj_gemm(
    const float* __restrict__ Xq, const float* __restrict__ Xk,
    const float* __restrict__ Xv,
    const float* __restrict__ Wq, const float* __restrict__ Wk,
    const float* __restrict__ Wv,
    const float* __restrict__ bq, const float* __restrict__ bk,
    const float* __restrict__ bv,
    unsigned short* __restrict__ dst_base)
{
  __shared__ __align__(16) unsigned short a_lds[128 * 32];
  __shared__ __align__(16) unsigned short b_lds[128 * 32];
  __shared__ __align__(16) unsigned short c_lds[64 * 136];  // stride 136: 16B-aligned, 2-way-free

  const int z = blockIdx.z;
  const float* X = (z == 0) ? Xq : ((z == 1) ? Xk : Xv);
  const float* W = (z == 0) ? Wq : ((z == 1) ? Wk : Wv);
  const float* bias = (z == 0) ? bq : ((z == 1) ? bk : bv);
  unsigned short* dst = dst_base + (size_t)z * NHEAD * LSEQ * 64;

  const int tid = threadIdx.x;
  const int wave = tid >> 6, lane = tid & 63;
  const int quad = lane >> 4, l16 = lane & 15;
  const int wm = (wave >> 1) * 64, wn = (wave & 1) * 64;
  const int bm = blockIdx.y * 128, bn = blockIdx.x * 128;

  v4f acc[4][4];
  for (int i = 0; i < 4; ++i)
    for (int j = 0; j < 4; ++j)
      acc[i][j] = (v4f){0.f, 0.f, 0.f, 0.f};

  const int row_s = tid >> 2;         // 0..63
  const int c8_s = (tid & 3) * 8;     // 0,8,16,24

  for (int k0 = 0; k0 < HDIM; k0 += 32) {
    __syncthreads();
    for (int s = 0; s < 2; ++s) {
      int row = row_s + s * 64;
      *(short8*)&a_lds[row * 32 + c8_s] = ld8(X, (size_t)(bm + row) * HDIM + k0 + c8_s);
      *(short8*)&b_lds[row * 32 + c8_s] = ld8(W, (size_t)(bn + row) * HDIM + k0 + c8_s);
    }
    __syncthreads();

    short8 af[4], bfr[4];
    for (int i = 0; i < 4; ++i)
      af[i] = *(const short8*)&a_lds[(wm + i * 16 + l16) * 32 + quad * 8];
    for (int j = 0; j < 4; ++j)
      bfr[j] = *(const short8*)&b_lds[(wn + j * 16 + l16) * 32 + quad * 8];
    if (z == 2) {
      // swapped operands: acc[i][j] holds C^T: row = n (d-dim), col = m (seq)
      for (int i = 0; i < 4; ++i)
        for (int j = 0; j < 4; ++j)
          acc[i][j] = __builtin_amdgcn_mfma_f32_16x16x32_bf16(bfr[j], af[i], acc[i][j], 0, 0, 0);
    } else {
      for (int i = 0; i < 4; ++i)
        for (int j = 0; j < 4; ++j)
          acc[i][j] = __builtin_amdgcn_mfma_f32_16x16x32_bf16(af[i], bfr[j], acc[i][j], 0, 0, 0);
    }
  }

  // ---- epilogue: two 64-row passes through c_lds, coalesced b128 stores ----
  // z<2 : C[m][n], LDS rows = m-local.  m = wm + i*16 + quad*4 + r, n = wn + j*16 + l16
  // z==2: C[n][m], LDS rows = n-local.  n = wn + j*16 + quad*4 + r, m = wm + i*16 + l16
  for (int p = 0; p < 2; ++p) {
    __syncthreads();
    if (z == 2) {
      if ((wave & 1) == p) {
        for (int j = 0; j < 4; ++j)
          for (int r = 0; r < 4; ++r) {
            float bv = bias[bn + wn + j * 16 + quad * 4 + r];
            int row = j * 16 + quad * 4 + r;
            for (int i = 0; i < 4; ++i)
              c_lds[row * 136 + wm + i * 16 + l16] = f2bf(acc[i][j][r] + bv);
          }
      }
    } else {
      if ((wave >> 1) == p) {
        for (int j = 0; j < 4; ++j) {
          float bv = bias[bn + wn + j * 16 + l16];
          for (int i = 0; i < 4; ++i)
            for (int r = 0; r < 4; ++r)
              c_lds[(i * 16 + quad * 4 + r) * 136 + wn + j * 16 + l16] =
                  f2bf(acc[i][j][r] + bv);
        }
      }
    }
    __syncthreads();
    // store 64 rows x 128 cols; thread t: row = t>>2, 32-col chunk c = t&3
    int row = tid >> 2, c = tid & 3;
    const unsigned short* srow = &c_lds[row * 136 + c * 32];
    if (z == 2) {
      int n = bn + p * 64 + row;            // d-dim
      int hh = n >> 6, d = n & 63;
      unsigned short* drow = dst + ((size_t)hh * 64 + d) * LSEQ + bm + c * 32;
      for (int q8 = 0; q8 < 4; ++q8)
        *(u32x4*)(drow + q8 * 8) = *(const u32x4*)(srow + q8 * 8);
    } else {
      int m = bm + p * 64 + row;
      int nbase = bn + c * 32;              // 32-chunk never crosses a head (÷64)
      int hh = nbase >> 6, d = nbase & 63;
      unsigned short* drow = dst + ((size_t)hh * LSEQ + m) * 64 + d;
      for (int q8 = 0; q8 < 4; ++q8)
        *(u32x4*)(drow + q8 * 8) = *(const u32x4*)(srow + q8 * 8);
    }
  }
}

// ---------------------------------------------------------------------------
// Flash attention, BK=128 key tiles, all LDS XOR-swizzled (chunk^=(row&7) in
// 16B units) -> conflict-free b128 fragment reads. No-max softmax (scores
// bounded, shift-invariant). grid = (64, 12), block = 256 (4 waves).
// ---------------------------------------------------------------------------
__global__ __launch_bounds__(256, 3) void attn(
    const unsigned short* __restrict__ Q, const unsigned short* __restrict__ K,
    const unsigned short* __restrict__ Vt, const float* __restrict__ mask,
    float* __restrict__ out)
{
  __shared__ __align__(16) unsigned short k_lds[128 * 64];    // [key][d]   chunk^(key&7)
  __shared__ __align__(16) unsigned short vt_lds[64 * 128];   // [d][key]   chunk^(d&7)
  __shared__ __align__(16) unsigned short p_lds[4][16 * 128]; // [wave][q][key] chunk^(q&7)

  const int h = blockIdx.y;
  const int qt = blockIdx.x;
  const int tid = threadIdx.x;
  const int wave = tid >> 6, lane = tid & 63;
  const int quad = lane >> 4, l16 = lane & 15;

  const unsigned short* Qh  = Q  + (size_t)h * LSEQ * 64;
  const unsigned short* Kh  = K  + (size_t)h * LSEQ * 64;
  const unsigned short* Vth = Vt + (size_t)h * 64 * LSEQ;

  const int qrow = qt * 64 + wave * 16;
  short8 qf[2];
  for (int c = 0; c < 2; ++c)
    qf[c] = *(const short8*)(Qh + (size_t)(qrow + l16) * 64 + c * 32 + quad * 8);

  v4f acc_o[4];
  for (int j = 0; j < 4; ++j) acc_o[j] = (v4f){0.f, 0.f, 0.f, 0.f};
  float lsum[4] = {0.f, 0.f, 0.f, 0.f};

  for (int kt = 0; kt < 32; ++kt) {
    const int key0 = kt * 128;

    // mask prefetch (L2-resident 16 KB; issue before barrier)
    float mk[8];
#pragma unroll
    for (int j = 0; j < 8; ++j) mk[j] = mask[key0 + j * 16 + l16] * 1.44269504f;

    __syncthreads();  // prior tile's LDS readers done
    // stage K tile: 128 rows x 8 chunks(16B); wave-load = 1 KB contiguous
#pragma unroll
    for (int s = 0; s < 4; ++s) {
      int ch = tid + 256 * s;                 // 0..1023
      int row = ch >> 3, c8 = ch & 7;
      *(u32x4*)&k_lds[row * 64 + ((c8 ^ (row & 7)) << 3)] =
          *(const u32x4*)(Kh + (size_t)(key0 + row) * 64 + c8 * 8);
    }
    // stage V^T tile: 64 rows x 16 chunks
#pragma unroll
    for (int s = 0; s < 4; ++s) {
      int ch = tid + 256 * s;
      int d = ch >> 4, kb = ch & 15;
      *(u32x4*)&vt_lds[d * 128 + ((kb ^ (d & 7)) << 3)] =
          *(const u32x4*)(Vth + (size_t)d * LSEQ + key0 + kb * 8);
    }
    __syncthreads();

    // S = Q K^T : 16 q-rows x 128 keys, 16 MFMA
    v4f sacc[8];
#pragma unroll
    for (int j = 0; j < 8; ++j) sacc[j] = (v4f){0.f, 0.f, 0.f, 0.f};
#pragma unroll
    for (int c = 0; c < 2; ++c)
#pragma unroll
      for (int j = 0; j < 8; ++j) {
        int row = j * 16 + l16;
        short8 kf = *(const short8*)&k_lds[row * 64 + (((c * 4 + quad) ^ (row & 7)) << 3)];
        sacc[j] = __builtin_amdgcn_mfma_f32_16x16x32_bf16(qf[c], kf, sacc[j], 0, 0, 0);
      }

    // p = exp2(s*scale*log2e + mask*log2e); truncate to bf16; lsum from
    // the truncated value so the truncation bias cancels in p/sum(p).
#pragma unroll
    for (int j = 0; j < 8; ++j) {
#pragma unroll
      for (int r = 0; r < 4; ++r) {
        union { float f; unsigned u; } pu;
        pu.f = EXP2F(fmaf(sacc[j][r], 0.18033688f, mk[j]));
        pu.u &= 0xffff0000u;
        lsum[r] += pu.f;
        int row = quad * 4 + r, col = j * 16 + l16;
        p_lds[wave][row * 128 + (((col >> 3) ^ (row & 7)) << 3) + (col & 7)] =
            (unsigned short)(pu.u >> 16);
      }
    }
    short8 pf[4];
#pragma unroll
    for (int c = 0; c < 4; ++c)
      pf[c] = *(const short8*)&p_lds[wave][l16 * 128 + (((c * 4 + quad) ^ (l16 & 7)) << 3)];

    // O += P V : 16 MFMA
#pragma unroll
    for (int kk = 0; kk < 4; ++kk)
#pragma unroll
      for (int j = 0; j < 4; ++j) {
        int d = j * 16 + l16;
        short8 vf = *(const short8*)&vt_lds[d * 128 + (((kk * 4 + quad) ^ (d & 7)) << 3)];
        acc_o[j] = __builtin_amdgcn_mfma_f32_16x16x32_bf16(pf[kk], vf, acc_o[j], 0, 0, 0);
      }
  }

  // final reduction of row sums over the 16 l16 lanes (row = quad*4+r)
  for (int r = 0; r < 4; ++r) {
    float s = lsum[r];
    for (int off = 8; off; off >>= 1) s += __shfl_xor(s, off, 64);
    lsum[r] = s;
  }

  // epilogue: out[l][h*64 + d] fp32
  for (int j = 0; j < 4; ++j) {
    int col = h * 64 + j * 16 + l16;
    for (int r = 0; r < 4; ++r) {
      int row = qt * 64 + wave * 16 + quad * 4 + r;
      out[(size_t)row * HDIM + col] = acc_o[j][r] / lsum[r];
    }
  }
}

extern "C" void kernel_launch(void* const* d_in, const int* in_sizes, int n_in,
                              void* d_out, int out_size, void* d_ws, size_t ws_size,
                              hipStream_t stream) {
  const float* query = (const float*)d_in[0];
  const float* key   = (const float*)d_in[1];
  const float* value = (const float*)d_in[2];
  const float* mask  = (const float*)d_in[3];
  const float* Wq = (const float*)d_in[4];
  const float* bq = (const float*)d_in[5];
  const float* Wk = (const float*)d_in[6];
  const float* bk = (const float*)d_in[7];
  const float* Wv = (const float*)d_in[8];
  const float* bv = (const float*)d_in[9];
  float* out = (float*)d_out;

  // ws usage: exactly 3 * NHEAD*LSEQ*64 bf16 = 18,874,368 bytes (known-safe bound).
  unsigned short* Qb = (unsigned short*)d_ws;                  // [NH][L][64] bf16
  unsigned short* Kb = Qb + (size_t)NHEAD * LSEQ * 64;         // [NH][L][64] bf16
  unsigned short* Vb = Kb + (size_t)NHEAD * LSEQ * 64;         // [NH][64][L] bf16 (transposed)

  proj_gemm<<<dim3(HDIM / 128, LSEQ / 128, 3), 256, 0, stream>>>(
      query, key, value, Wq, Wk, Wv, bq, bk, bv, Qb);
  attn<<<dim3(LSEQ / 64, NHEAD), 256, 0, stream>>>(Qb, Kb, Vb, mask, out);
}